// Round 7
// baseline (764.983 us; speedup 1.0000x reference)
//
#include <hip/hip_runtime.h>
#include <hip/hip_bf16.h>

// LinkPredictorGAT: out[e] = relu(concat(z[src[e]], z[dst[e]]) @ W1 + b1) @ W2 + b2
// R6: full B^T resident in LDS (128 KB, XOR-swizzled, unpadded), staged once by a
// persistent 512-thread block (1/CU); steady-state K-loop has ZERO barriers, zero
// LDS writes, zero staging — only A-gather + swizzled ds_read_b128 + MFMA.
// Evidence: R2(16 barriers)=262us, R5(8)=217us -> ~5.6us/barrier (compiler drains
// vmcnt(0) at every s_barrier, killing prefetch); R4 proved 139KB static LDS works;
// R5's 2e7 bank-conflict cycles came from stride-17 padding (XOR swizzle is free).

typedef __attribute__((ext_vector_type(4))) float floatx4;
typedef __attribute__((ext_vector_type(8))) short short8;

__device__ __forceinline__ unsigned short bf16rne(float x) {
    unsigned int u = __float_as_uint(x);
    u += 0x7fffu + ((u >> 16) & 1u);
    return (unsigned short)(u >> 16);
}

// ---- convert z (fp32 -> bf16), float4 per thread ----
__global__ void cvt_z(const float* __restrict__ z, unsigned short* __restrict__ zb, int n4) {
    int i = blockIdx.x * blockDim.x + threadIdx.x;
    if (i < n4) {
        float4 f = ((const float4*)z)[i];
        ushort4 u;
        u.x = bf16rne(f.x); u.y = bf16rne(f.y);
        u.z = bf16rne(f.z); u.w = bf16rne(f.w);
        ((ushort4*)zb)[i] = u;
    }
}

// ---- convert W1 [512][128] fp32 -> BTc, the EXACT (swizzled) LDS image of B^T ----
// LDS/BTc layout (shorts): L(s,n,g',j) = s*4096 + n*32 + g'*8 + j
//   s = k>>5 (K32 slab), g = (k>>3)&3, j = k&7, swizzle g' = g ^ ((n>>1)&3).
// Reader lane (l15,quad) for col n=nf*16+l15 reads g = quad at g' = quad^((l15>>1)&3):
// dword bank = 16*(n&1) + 4*(quad^swz) -> each (parity,group) cell gets exactly 2
// lanes per quad-phase -> 2-way aliasing = free (m136), no padding needed.
__global__ void cvt_w1(const float* __restrict__ W1, unsigned short* __restrict__ BTc) {
    int t = blockIdx.x * blockDim.x + threadIdx.x;   // 0..65535
    int s = t >> 12, rem = t & 4095;
    int n = rem >> 5, rem2 = rem & 31;
    int gp = rem2 >> 3, j = rem2 & 7;
    int g = gp ^ ((n >> 1) & 3);
    int k = s * 32 + g * 8 + j;
    BTc[t] = bf16rne(W1[k * 128 + n]);
}

// ---- fused gather + GEMM(512x128) + bias + relu + GEMV(W2) ----
// 512 threads = 8 waves, persistent (grid <= 256, 1 block/CU due to 128 KB LDS).
// Wave tile 64 edges x 128 cols (mf=4, nf=8); tile = 512 edges/block.
template <bool ABF16>
__global__ __launch_bounds__(512, 2)   // 2 waves/EU -> 256 unified regs/wave
void fused_mlp(const float* __restrict__ zf, const unsigned short* __restrict__ zb,
               const int* __restrict__ eli, int E, int nnodes,
               const unsigned short* __restrict__ BTc,
               const float* __restrict__ b1, const float* __restrict__ W2,
               const float* __restrict__ b2, float* __restrict__ out, int ntiles)
{
    __shared__ unsigned short btile[16 * 128 * 32];   // 128 KB, swizzled image of BTc

    const int t = threadIdx.x;
    const int wid = t >> 6;
    const int lane = t & 63;
    const int l15 = lane & 15;
    const int quad = lane >> 4;

    // ---- one-time stage: flat 128 KB copy (BTc already swizzled), coalesced ----
#pragma unroll
    for (int i = 0; i < 16; ++i) {
        int p = i * 512 + t;                          // 8192 pieces of 8 shorts
        *(short8*)&btile[p * 8] = *(const short8*)(BTc + p * 8);
    }
    __syncthreads();                                  // the ONLY barrier

    const char* zbb = (const char*)(ABF16 ? (const void*)zb : (const void*)zf);
    // lane-constant part of B fragment address (shorts): l15*32 + (quad^swz)*8
    const int swz = (l15 >> 1) & 3;
    const unsigned short* bbase = btile + l15 * 32 + (quad ^ swz) * 8;

    for (int tile = blockIdx.x; tile < ntiles; tile += gridDim.x) {
        const int m0 = tile * 512 + wid * 64;         // this wave's first edge

        unsigned offs[4], offd[4];
#pragma unroll
        for (int mf = 0; mf < 4; ++mf) {
            int e = m0 + mf * 16 + l15;
            e = e < E ? e : E - 1;                    // clamp tail (stores masked later)
            int s = eli[e];
            int d = eli[E + e];
            s = s < 0 ? 0 : (s >= nnodes ? nnodes - 1 : s);
            d = d < 0 ? 0 : (d >= nnodes ? nnodes - 1 : d);
            offs[mf] = (unsigned)s * 512u;            // bf16 row = 512 B
            offd[mf] = (unsigned)d * 512u;
        }

        floatx4 acc[4][8];
#pragma unroll
        for (int mf = 0; mf < 4; ++mf)
#pragma unroll
            for (int nf = 0; nf < 8; ++nf)
                acc[mf][nf] = (floatx4){0.f, 0.f, 0.f, 0.f};

        auto load_a = [&](int ks, short8* dst) {      // ks in [0,16)
            const unsigned* off = (ks < 8) ? offs : offd;
            if constexpr (ABF16) {
                const int cbytes = (ks & 7) * 64 + quad * 16;
#pragma unroll
                for (int mf = 0; mf < 4; ++mf)
                    dst[mf] = *(const short8*)(zbb + (size_t)off[mf] + cbytes);
            } else {
                const int cbytes = (ks & 7) * 128 + quad * 32;
#pragma unroll
                for (int mf = 0; mf < 4; ++mf) {
                    const float* pf = (const float*)(zbb + (size_t)off[mf] * 2 + cbytes);
                    float4 f0 = *(const float4*)pf;
                    float4 f1 = *(const float4*)(pf + 4);
                    short8 av;
                    av[0] = (short)bf16rne(f0.x); av[1] = (short)bf16rne(f0.y);
                    av[2] = (short)bf16rne(f0.z); av[3] = (short)bf16rne(f0.w);
                    av[4] = (short)bf16rne(f1.x); av[5] = (short)bf16rne(f1.y);
                    av[6] = (short)bf16rne(f1.z); av[7] = (short)bf16rne(f1.w);
                    dst[mf] = av;
                }
            }
        };

        short8 A[2][4];                               // depth-1 rolling prefetch
        load_a(0, A[0]);                              // (~621 cyc/k-step at full MFMA
                                                      //  rate >= L3 gather latency)
#pragma unroll
        for (int ks = 0; ks < 16; ++ks) {
            if (ks < 15) load_a(ks + 1, A[(ks + 1) & 1]);

            const unsigned short* bslab = bbase + ks * 4096;   // K32 slab, 8 KB
            short8 bfr[8];
#pragma unroll
            for (int nf = 0; nf < 8; ++nf)
                bfr[nf] = *(const short8*)(bslab + nf * 512);  // swizzled, conflict-free

            const short8* ac = A[ks & 1];
#pragma unroll
            for (int nf = 0; nf < 8; ++nf)
#pragma unroll
                for (int mf = 0; mf < 4; ++mf)
                    acc[mf][nf] = __builtin_amdgcn_mfma_f32_16x16x32_bf16(
                        ac[mf], bfr[nf], acc[mf][nf], 0, 0, 0);
        }

        // ---- epilogue (consts loaded late; C/D: col=lane&15+16nf, row=quad*4+r+16mf) ----
        const float b2s = b2[0];
        float b1v[8], w2v[8];
#pragma unroll
        for (int nf = 0; nf < 8; ++nf) {
            int c = nf * 16 + l15;
            b1v[nf] = b1[c];
            w2v[nf] = W2[c];
        }
#pragma unroll
        for (int mf = 0; mf < 4; ++mf) {
#pragma unroll
            for (int r = 0; r < 4; ++r) {
                float s = 0.f;
#pragma unroll
                for (int nf = 0; nf < 8; ++nf) {
                    float v = acc[mf][nf][r] + b1v[nf];
                    v = v > 0.f ? v : 0.f;
                    s = fmaf(v, w2v[nf], s);
                }
                s += __shfl_xor(s, 1);
                s += __shfl_xor(s, 2);
                s += __shfl_xor(s, 4);
                s += __shfl_xor(s, 8);
                if (l15 == 0) {
                    int e = m0 + mf * 16 + quad * 4 + r;
                    if (e < E) out[e] = s + b2s;
                }
            }
        }
    }
}

// ---- emergency fallback (tiny ws): one block per edge, fp32 vector ----
__global__ void naive_edge(const float* __restrict__ z, const int* __restrict__ eli,
                           int E, int nnodes,
                           const float* __restrict__ W1, const float* __restrict__ b1,
                           const float* __restrict__ W2, const float* __restrict__ b2,
                           float* __restrict__ out)
{
    __shared__ float red[2];
    int e = blockIdx.x;
    int j = threadIdx.x;
    int s = eli[e], d = eli[E + e];
    s = s < 0 ? 0 : (s >= nnodes ? nnodes - 1 : s);
    d = d < 0 ? 0 : (d >= nnodes ? nnodes - 1 : d);
    const float* zs = z + (long long)s * 256;
    const float* zd = z + (long long)d * 256;
    float h = b1[j];
    for (int i = 0; i < 256; ++i) h = fmaf(zs[i], W1[i * 128 + j], h);
    for (int i = 0; i < 256; ++i) h = fmaf(zd[i], W1[(256 + i) * 128 + j], h);
    h = h > 0.f ? h : 0.f;
    float v = h * W2[j];
    v += __shfl_xor(v, 1);  v += __shfl_xor(v, 2);  v += __shfl_xor(v, 4);
    v += __shfl_xor(v, 8);  v += __shfl_xor(v, 16); v += __shfl_xor(v, 32);
    if ((threadIdx.x & 63) == 0) red[threadIdx.x >> 6] = v;
    __syncthreads();
    if (threadIdx.x == 0) out[e] = red[0] + red[1] + b2[0];
}

extern "C" void kernel_launch(void* const* d_in, const int* in_sizes, int n_in,
                              void* d_out, int out_size, void* d_ws, size_t ws_size,
                              hipStream_t stream) {
    const float* z   = (const float*)d_in[0];
    const int*   eli = (const int*)d_in[1];      // int64 in reference -> int32 on device
    const float* W1  = (const float*)d_in[2];
    const float* b1  = (const float*)d_in[3];
    const float* W2  = (const float*)d_in[4];
    const float* b2  = (const float*)d_in[5];
    float*       out = (float*)d_out;

    const int E      = in_sizes[1] / 2;
    const int nnodes = in_sizes[0] / 256;

    const size_t ZB  = (size_t)nnodes * 256 * 2;   // z in bf16
    const size_t BTB = (size_t)512 * 128 * 2;      // B^T (swizzled image) in bf16

    const int ntiles = (E + 511) / 512;
    const int grid_main = ntiles < 256 ? ntiles : 256;   // persistent, 1 block/CU

    if (ws_size >= ZB + BTB) {
        unsigned short* zb  = (unsigned short*)d_ws;
        unsigned short* BTc = (unsigned short*)((char*)d_ws + ZB);
        int n4 = nnodes * 64;
        cvt_z<<<(n4 + 255) / 256, 256, 0, stream>>>(z, zb, n4);
        cvt_w1<<<256, 256, 0, stream>>>(W1, BTc);
        fused_mlp<true><<<grid_main, 512, 0, stream>>>(nullptr, zb, eli, E, nnodes, BTc, b1, W2, b2, out, ntiles);
    } else if (ws_size >= BTB) {
        unsigned short* BTc = (unsigned short*)d_ws;
        cvt_w1<<<256, 256, 0, stream>>>(W1, BTc);
        fused_mlp<false><<<grid_main, 512, 0, stream>>>(z, nullptr, eli, E, nnodes, BTc, b1, W2, b2, out, ntiles);
    } else {
        naive_edge<<<E, 128, 0, stream>>>(z, eli, E, nnodes, W1, b1, W2, b2, out);
    }
}